// Round 3
// baseline (319.586 us; speedup 1.0000x reference)
//
#include <hip/hip_runtime.h>

#define N_Q  100000
#define N_M  5000
#define NP   5120            // maze table padded to CH*LCH
#define BLK  256
#define CH   8               // lanes (M-chunks) per query
#define LCH  (NP / CH)       // 640 points per lane
#define SUB  32              // bookkeeping sub-block (points)
#define NSUB (LCH / SUB)     // 20
#define QPB  (BLK / CH)      // 32 queries per block

typedef float v2f __attribute__((ext_vector_type(2)));

// Packed fp32: two independent IEEE fp32 ops per instruction (CDNA dual-issue).
// Component-wise results are bit-identical to scalar v_add_f32 / v_mul_f32.
#define PK_ADD(d, a, b) asm("v_pk_add_f32 %0, %1, %2" : "=v"(d) : "v"(a), "v"(b))
#define PK_MUL(d, a, b) asm("v_pk_mul_f32 %0, %1, %2" : "=v"(d) : "v"(a), "v"(b))
#define MIN3(d, a, b, c) asm("v_min3_f32 %0, %1, %2, %3" : "=v"(d) : "v"(a), "v"(b), "v"(c))

__global__ __launch_bounds__(BLK) void nn1_kernel(
    const float* __restrict__ q,
    const float* __restrict__ maze,
    const float* __restrict__ ts,
    float* __restrict__ out)
{
    // SoA, pre-NEGATED maze coords (so dx = x + (-px): plain pk_add, no
    // modifier syntax risk; a-b == a+(-b) exactly in IEEE). Pad with 1e30
    // -> d2 = +inf, never wins, never matches at rescan.
    __shared__ float snx[NP];
    __shared__ float sny[NP];
    const float2* mz = (const float2*)maze;
    for (int i = threadIdx.x; i < NP; i += BLK) {
        float px = 1e30f, py = 1e30f;
        if (i < N_M) { float2 p = mz[i]; px = p.x; py = p.y; }
        snx[i] = -px;
        sny[i] = -py;
    }
    __syncthreads();

    const int t  = threadIdx.x;
    const int qi = blockIdx.x * QPB + (t >> 3);   // grid*QPB == N_Q exactly
    const int c  = t & 7;

    const float2 xq = ((const float2*)q)[qi];
    const v2f xx = { xq.x, xq.x };
    const v2f yy = { xq.y, xq.y };

    // ---- pass 1: value-min only, track which SUB-block holds it ----
    float runbest  = 3.4e38f;
    int   bestbase = c * LCH;
    for (int b = 0; b < NSUB; ++b) {
        const int base = c * LCH + b * SUB;
        float bmin = 3.4e38f;
        #pragma unroll
        for (int g = 0; g < SUB / 4; ++g) {
            const int o = base + g * 4;
            float4 nx4 = *(const float4*)&snx[o];   // ds_read_b128
            float4 ny4 = *(const float4*)&sny[o];
            v2f nxa = { nx4.x, nx4.y }, nxb = { nx4.z, nx4.w };
            v2f nya = { ny4.x, ny4.y }, nyb = { ny4.z, ny4.w };
            v2f dxa, dya, dxb, dyb, xa2, ya2, xb2, yb2, d2a, d2b;
            PK_ADD(dxa, xx, nxa);
            PK_ADD(dya, yy, nya);
            PK_MUL(xa2, dxa, dxa);
            PK_MUL(ya2, dya, dya);
            PK_ADD(d2a, xa2, ya2);
            PK_ADD(dxb, xx, nxb);
            PK_ADD(dyb, yy, nyb);
            PK_MUL(xb2, dxb, dxb);
            PK_MUL(yb2, dyb, dyb);
            PK_ADD(d2b, xb2, yb2);
            float m1;
            MIN3(m1, d2a.x, d2a.y, bmin);
            MIN3(bmin, d2b.x, d2b.y, m1);
        }
        // strict < keeps the EARLIEST block on cross-block ties (argmin
        // first-occurrence). min itself is exact (no rounding).
        if (bmin < runbest) { runbest = bmin; bestbase = base; }
    }

    // ---- pass 2: rescan the winning 32-point block for the first index
    // whose d2 equals the min. Recomputation uses the identical IEEE op
    // sequence (add, mul, mul, add) -> bit-equal compare.
    const float best = runbest;
    int midx = 0x7fffffff;
    #pragma unroll 4
    for (int k = 0; k < SUB; ++k) {
        const int gi = bestbase + k;
        float dx = __fadd_rn(xq.x, snx[gi]);
        float dy = __fadd_rn(xq.y, sny[gi]);
        float d2 = __fadd_rn(__fmul_rn(dx, dx), __fmul_rn(dy, dy));
        if (d2 == best && gi < midx) midx = gi;   // ascending -> first match
    }

    // ---- merge the 8 chunk-lanes: lexicographic (d2, idx) min ----
    float mbest = best;
    int   mbidx = midx;
    #pragma unroll
    for (int s = 1; s < CH; s <<= 1) {
        float ob = __shfl_xor(mbest, s);
        int   oi = __shfl_xor(mbidx, s);
        if (ob < mbest || (ob == mbest && oi < mbidx)) { mbest = ob; mbidx = oi; }
    }

    if (c == 0) {
        const float2 bp = mz[mbidx];
        out[2 * qi]       = bp.x;
        out[2 * qi + 1]   = bp.y;
        out[2 * N_Q + qi] = ts[mbidx];
    }
}

extern "C" void kernel_launch(void* const* d_in, const int* in_sizes, int n_in,
                              void* d_out, int out_size, void* d_ws, size_t ws_size,
                              hipStream_t stream) {
    const float* q    = (const float*)d_in[0];  // euclidean_data [N,2]
    const float* maze = (const float*)d_in[1];  // maze_points   [M,2]
    const float* ts   = (const float*)d_in[2];  // ts_proj       [M]
    float* out = (float*)d_out;                 // [N*2] proj_pos ++ [N] linear_pos

    const int grid = N_Q / QPB;                 // 3125, exact
    nn1_kernel<<<grid, BLK, 0, stream>>>(q, maze, ts, out);
}

// Round 4
// 73.018 us; speedup vs baseline: 4.3768x; 4.3768x over previous
//
#include <hip/hip_runtime.h>

#define N_Q  100000
#define N_M  5000
#define CH   8               // chunks (lanes) per query
#define LCH  640             // points per chunk
#define NP   (CH * LCH)      // 5120 (padded)
#define SUB  16              // points per bookkeeping sub-block
#define NSUB (LCH / SUB)     // 40
#define FPS  (SUB / 2)       // 8 float4 per sub-block
#define BLK  256
#define QPW  16              // queries per wave (8 groups x 2 per lane)
#define QPB  64              // queries per block (4 waves)

typedef float v2f __attribute__((ext_vector_type(2)));

// Packed fp32 (CDNA): component-wise bit-identical to scalar v_add/v_mul.
#define PK_ADD(d, a, b) asm("v_pk_add_f32 %0, %1, %2" : "=v"(d) : "v"(a), "v"(b))
#define PK_MUL(d, a, b) asm("v_pk_mul_f32 %0, %1, %2" : "=v"(d) : "v"(a), "v"(b))
#define MIN3(d, a, b, c) asm("v_min3_f32 %0, %1, %2, %3" : "=v"(d) : "v"(a), "v"(b), "v"(c))

__global__ __launch_bounds__(BLK) void nn1_kernel(
    const float* __restrict__ q,
    const float* __restrict__ maze,
    const float* __restrict__ ts,
    float* __restrict__ out)
{
    // Interleaved, NEGATED maze table: float4 slot (f, c) at float4-index
    // f*CH + c  -> byte addr (f*8+c)*16 -> the wave's 8 distinct chunk
    // addresses cover all 32 banks exactly once (banks 4c..4c+3); the 8
    // lanes sharing c broadcast. Pass-1 is conflict-free by construction
    // (R3's 640-word chunk stride was 0 mod 32 -> 8-way conflict, 78% stall).
    __shared__ float4 sm[(LCH / 2) * CH];   // 2560 float4 = 40960 B
    const float2* mz = (const float2*)maze;
    for (int i = threadIdx.x; i < NP; i += BLK) {
        const int c = i / LCH, k = i - c * LCH;
        float px = 1e30f, py = 1e30f;            // pad -> d2 = +inf, never wins
        if (i < N_M) { float2 p = mz[i]; px = p.x; py = p.y; }
        ((float2*)sm)[((k >> 1) * CH + c) * 2 + (k & 1)] = make_float2(-px, -py);
    }
    __syncthreads();

    const int t    = threadIdx.x;
    const int lane = t & 63;
    const int g    = lane >> 3;            // query group 0..7
    const int c    = lane & 7;             // chunk 0..7
    const int qb   = blockIdx.x * QPB + (t >> 6) * QPW + g;
    const int qi0  = qb, qi1 = qb + 8;     // 2 queries per lane share LDS reads

    const float2 qa = ((const float2*)q)[qi0 < N_Q ? qi0 : N_Q - 1];
    const float2 qc = ((const float2*)q)[qi1 < N_Q ? qi1 : N_Q - 1];
    const v2f qva = { qa.x, qa.y };
    const v2f qvb = { qc.x, qc.y };

    const float4* base = &sm[c];           // stride CH float4 per f-slot

    // ---- pass 1: packed distance + min3 value-min; track winning sub-block.
    // numpy-exact per point: dx=x+(-px), dy=y+(-py), d2=rn(rn(dx*dx)+rn(dy*dy)).
    float run0 = 3.4e38f, run1 = 3.4e38f;
    int   bb0 = 0, bb1 = 0;
    for (int b = 0; b < NSUB; ++b) {
        float bm0 = 3.4e38f, bm1 = 3.4e38f;
        #pragma unroll
        for (int fi = 0; fi < FPS; ++fi) {
            const float4 pp = base[(b * FPS + fi) * CH];   // ds_read_b128
            const v2f p0 = { pp.x, pp.y }, p1 = { pp.z, pp.w };
            v2f e0, s0, e1, s1, f0, u0, f1, u1;
            PK_ADD(e0, qva, p0); PK_MUL(s0, e0, e0);
            PK_ADD(e1, qva, p1); PK_MUL(s1, e1, e1);
            PK_ADD(f0, qvb, p0); PK_MUL(u0, f0, f0);
            PK_ADD(f1, qvb, p1); PK_MUL(u1, f1, f1);
            const float d0a = __fadd_rn(s0.x, s0.y);
            const float d1a = __fadd_rn(s1.x, s1.y);
            const float d0b = __fadd_rn(u0.x, u0.y);
            const float d1b = __fadd_rn(u1.x, u1.y);
            MIN3(bm0, d0a, d1a, bm0);
            MIN3(bm1, d0b, d1b, bm1);
        }
        // strict < keeps the earliest sub-block on ties (first-occurrence).
        if (bm0 < run0) { run0 = bm0; bb0 = b; }
        if (bm1 < run1) { run1 = bm1; bb1 = b; }
    }

    // ---- pass 2: rescan winning sub-block; recompute with the identical
    // IEEE op sequence -> bit-equal compare recovers the first index.
    auto rescan = [&](float best, int bb, v2f qv) -> int {
        int midx = 0x7fffffff;
        #pragma unroll
        for (int fi = 0; fi < FPS; ++fi) {
            const float4 pp = base[(bb * FPS + fi) * CH];
            const v2f p0 = { pp.x, pp.y }, p1 = { pp.z, pp.w };
            v2f e0, s0, e1, s1;
            PK_ADD(e0, qv, p0); PK_MUL(s0, e0, e0);
            PK_ADD(e1, qv, p1); PK_MUL(s1, e1, e1);
            const float d0 = __fadd_rn(s0.x, s0.y);
            const float d1 = __fadd_rn(s1.x, s1.y);
            const int gi = c * LCH + bb * SUB + fi * 2;
            if (d0 == best && gi     < midx) midx = gi;
            if (d1 == best && gi + 1 < midx) midx = gi + 1;
        }
        return midx;
    };
    int mi0 = rescan(run0, bb0, qva);
    int mi1 = rescan(run1, bb1, qvb);

    // ---- merge the 8 chunk-lanes: lexicographic (d2, idx) min.
    float v0 = run0, v1 = run1;
    #pragma unroll
    for (int s = 1; s < CH; s <<= 1) {
        const float o0 = __shfl_xor(v0, s);
        const int   j0 = __shfl_xor(mi0, s);
        if (o0 < v0 || (o0 == v0 && j0 < mi0)) { v0 = o0; mi0 = j0; }
        const float o1 = __shfl_xor(v1, s);
        const int   j1 = __shfl_xor(mi1, s);
        if (o1 < v1 || (o1 == v1 && j1 < mi1)) { v1 = o1; mi1 = j1; }
    }

    if (c == 0) {
        mi0 = mi0 < N_M ? mi0 : N_M - 1;   // safety clamp (no-op if correct)
        mi1 = mi1 < N_M ? mi1 : N_M - 1;
        if (qi0 < N_Q) {
            const float2 bp = mz[mi0];
            out[2 * qi0] = bp.x; out[2 * qi0 + 1] = bp.y;
            out[2 * N_Q + qi0] = ts[mi0];
        }
        if (qi1 < N_Q) {
            const float2 bp = mz[mi1];
            out[2 * qi1] = bp.x; out[2 * qi1 + 1] = bp.y;
            out[2 * N_Q + qi1] = ts[mi1];
        }
    }
}

extern "C" void kernel_launch(void* const* d_in, const int* in_sizes, int n_in,
                              void* d_out, int out_size, void* d_ws, size_t ws_size,
                              hipStream_t stream) {
    const float* q    = (const float*)d_in[0];  // euclidean_data [N,2]
    const float* maze = (const float*)d_in[1];  // maze_points   [M,2]
    const float* ts   = (const float*)d_in[2];  // ts_proj       [M]
    float* out = (float*)d_out;                 // [N*2] proj_pos ++ [N] linear_pos

    const int grid = (N_Q + QPB - 1) / QPB;     // 1563
    nn1_kernel<<<grid, BLK, 0, stream>>>(q, maze, ts, out);
}

// Round 5
// 66.037 us; speedup vs baseline: 4.8395x; 1.1057x over previous
//
#include <hip/hip_runtime.h>

#define N_Q  100000
#define N_M  5000
#define CW   4               // chunks = waves per block
#define CHK  1264            // padded chunk length (79 * 16)
#define NSUB 79              // 16-pt sub-blocks per chunk
#define NPAD (CW * CHK)      // 5056 floats per stream
#define WS_BYTES (NPAD * 2 * 4)   // 40448

typedef float v2f __attribute__((ext_vector_type(2)));
typedef float v8f __attribute__((ext_vector_type(8)));

// ---------------- setup: negated SoA maze table in d_ws ----------------
// ws[0..5055]    = -x (pads +1e30 -> d2 = inf, never wins / never matches)
// ws[5056..]     = -y
__global__ void setup_soa(const float* __restrict__ maze, float* __restrict__ ws) {
    const int i = blockIdx.x * 256 + threadIdx.x;
    if (i >= NPAD) return;
    const int c = i / CHK, k = i - c * CHK;
    float x = 1e30f, y = 1e30f;
    const int g = c * 1250 + k;
    if (k < 1250) { x = -maze[2 * g]; y = -maze[2 * g + 1]; }
    ws[i] = x;
    ws[NPAD + i] = y;
}

// ---------------- main scan ----------------
// s_load issue (volatile asm keeps order among volatiles):
#define LDX0(D) asm volatile("s_load_dwordx8 %0, %1, 0x0"    : "=s"(D) : "s"(xb))
#define LDX1(D) asm volatile("s_load_dwordx8 %0, %1, 0x20"   : "=s"(D) : "s"(xb))
#define LDY0(D) asm volatile("s_load_dwordx8 %0, %1, 0x4f00" : "=s"(D) : "s"(xb))
#define LDY1(D) asm volatile("s_load_dwordx8 %0, %1, 0x4f20" : "=s"(D) : "s"(xb))
// SMEM completes out-of-order -> only lgkmcnt(0) is safe; "+s" ties make the
// consumers data-depend on the post-wait values (no hoist past the wait).
#define WAIT4(a,b,c,d) asm volatile("s_waitcnt lgkmcnt(0)" : "+s"(a), "+s"(b), "+s"(c), "+s"(d))

// One packed step: points (2J, 2J+1) of an 8-float granule vs this lane's query.
// numpy-exact per point: dx=rn(qx+(-px)); d2=rn(rn(dx*dx)+rn(dy*dy)). No FMA.
// v_pk_* are component-wise IEEE fp32 (bit-identical to scalar v_add/v_mul).
#define PSTEP(X8, Y8, J) do {                                                 \
    v2f px_ = __builtin_shufflevector(X8, X8, 2*(J), 2*(J)+1);                \
    v2f py_ = __builtin_shufflevector(Y8, Y8, 2*(J), 2*(J)+1);                \
    v2f dx_, dy_;                                                             \
    asm("v_pk_add_f32 %0, %1, %2" : "=v"(dx_) : "s"(px_), "v"(qxx));          \
    asm("v_pk_add_f32 %0, %1, %2" : "=v"(dy_) : "s"(py_), "v"(qyy));          \
    asm("v_pk_mul_f32 %0, %0, %0" : "+v"(dx_));                               \
    asm("v_pk_mul_f32 %0, %0, %0" : "+v"(dy_));                               \
    asm("v_pk_add_f32 %0, %0, %1" : "+v"(dx_) : "v"(dy_));                    \
    float a_ = dx_.x, b_ = dx_.y;                                             \
    asm("v_min3_f32 %0, %1, %2, %0" : "+v"(bm) : "v"(a_), "v"(b_));           \
} while (0)

// bm is monotone; bb = sub-block of FIRST attainment of the running min
// (strict < -> earlier equal values keep the earlier block).
#define COMP(X0, X1, Y0, Y1, B) do {                                          \
    PSTEP(X0, Y0, 0); PSTEP(X0, Y0, 1); PSTEP(X0, Y0, 2); PSTEP(X0, Y0, 3);   \
    PSTEP(X1, Y1, 0); PSTEP(X1, Y1, 1); PSTEP(X1, Y1, 2); PSTEP(X1, Y1, 3);   \
    bb = (bm < prev) ? (B) : bb; prev = bm;                                   \
} while (0)

__global__ __launch_bounds__(256) void nn_scan(
    const float* __restrict__ q,
    const float* __restrict__ maze,
    const float* __restrict__ ts,
    const float* __restrict__ ws,
    float* __restrict__ out)
{
    __shared__ float sval[CW][64];
    __shared__ int   sidx[CW][64];

    const int lane = threadIdx.x & 63;
    const int wv   = __builtin_amdgcn_readfirstlane((int)(threadIdx.x >> 6)); // chunk id (uniform)
    const int qi   = blockIdx.x * 64 + lane;
    const int qc   = qi < N_Q ? qi : N_Q - 1;

    const float2 Q = ((const float2*)q)[qc];
    const v2f qxx = { Q.x, Q.x };
    const v2f qyy = { Q.y, Q.y };

    unsigned long long xb =
        (unsigned long long)(const void*)(ws + (size_t)wv * CHK);

    v8f ax0, ax1, ay0, ay1, bx0, bx1, by0, by1;
    LDX0(ax0); LDX1(ax1); LDY0(ay0); LDY1(ay1); xb += 64;   // block 0 -> A

    float bm = 3.4e38f, prev = 3.4e38f;
    int bb = 0;

    #pragma unroll 1
    for (int k = 0; k < 39; ++k) {               // blocks 2k and 2k+1
        WAIT4(ax0, ax1, ay0, ay1);
        LDX0(bx0); LDX1(bx1); LDY0(by0); LDY1(by1); xb += 64;   // block 2k+1 -> B
        COMP(ax0, ax1, ay0, ay1, 2 * k);
        WAIT4(bx0, bx1, by0, by1);
        LDX0(ax0); LDX1(ax1); LDY0(ay0); LDY1(ay1); xb += 64;   // block 2k+2 -> A (2k+2 <= 78)
        COMP(bx0, bx1, by0, by1, 2 * k + 1);
    }
    WAIT4(ax0, ax1, ay0, ay1);
    COMP(ax0, ax1, ay0, ay1, 78);

    // rescan winning 16-pt sub-block (per-lane vector gather, L2-resident);
    // identical IEEE op sequence -> bit-equal compare; ascending -> first index.
    int fk = 0x7fffffff;
    {
        const float* xs = ws + (size_t)wv * CHK + (size_t)bb * 16;
        #pragma unroll
        for (int j = 0; j < 16; ++j) {
            const float dx = __fadd_rn(Q.x, xs[j]);
            const float dy = __fadd_rn(Q.y, xs[j + NPAD]);
            const float d2 = __fadd_rn(__fmul_rn(dx, dx), __fmul_rn(dy, dy));
            if (d2 == bm) fk = min(fk, bb * 16 + j);
        }
    }
    const int kloc = fk < 1250 ? fk : 1249;      // safety clamp (no-op if correct)
    sval[wv][lane] = bm;
    sidx[wv][lane] = wv * 1250 + kloc;
    __syncthreads();

    // merge the 4 chunk-waves: lexicographic (d2, idx) = global first-occurrence
    if (wv == 0 && qi < N_Q) {
        float bv = sval[0][lane];
        int   bg = sidx[0][lane];
        #pragma unroll
        for (int c = 1; c < CW; ++c) {
            const float v = sval[c][lane];
            const int   g = sidx[c][lane];
            if (v < bv || (v == bv && g < bg)) { bv = v; bg = g; }
        }
        const float2 bp = ((const float2*)maze)[bg];
        out[2 * qi]       = bp.x;
        out[2 * qi + 1]   = bp.y;
        out[2 * N_Q + qi] = ts[bg];
    }
}

// ---------------- fallback (proven R4 kernel) if ws is too small ----------------
#define FCH   8
#define FLCH  640
#define FNP   (FCH * FLCH)
#define FSUB  16
#define FNSUB (FLCH / FSUB)
#define FFPS  (FSUB / 2)

#define FPK_ADD(d, a, b) asm("v_pk_add_f32 %0, %1, %2" : "=v"(d) : "v"(a), "v"(b))
#define FPK_MUL(d, a, b) asm("v_pk_mul_f32 %0, %1, %2" : "=v"(d) : "v"(a), "v"(b))
#define FMIN3(d, a, b, c) asm("v_min3_f32 %0, %1, %2, %3" : "=v"(d) : "v"(a), "v"(b), "v"(c))

__global__ __launch_bounds__(256) void nn1_fallback(
    const float* __restrict__ q, const float* __restrict__ maze,
    const float* __restrict__ ts, float* __restrict__ out)
{
    __shared__ float4 sm[(FLCH / 2) * FCH];
    const float2* mz = (const float2*)maze;
    for (int i = threadIdx.x; i < FNP; i += 256) {
        const int c = i / FLCH, k = i - c * FLCH;
        float px = 1e30f, py = 1e30f;
        if (i < N_M) { float2 p = mz[i]; px = p.x; py = p.y; }
        ((float2*)sm)[((k >> 1) * FCH + c) * 2 + (k & 1)] = make_float2(-px, -py);
    }
    __syncthreads();
    const int t = threadIdx.x, lane = t & 63, g = lane >> 3, c = lane & 7;
    const int qb = blockIdx.x * 64 + (t >> 6) * 16 + g;
    const int qi0 = qb, qi1 = qb + 8;
    const float2 qa = ((const float2*)q)[qi0 < N_Q ? qi0 : N_Q - 1];
    const float2 qc = ((const float2*)q)[qi1 < N_Q ? qi1 : N_Q - 1];
    const v2f qva = { qa.x, qa.y }, qvb = { qc.x, qc.y };
    const float4* base = &sm[c];
    float run0 = 3.4e38f, run1 = 3.4e38f; int bb0 = 0, bb1 = 0;
    for (int b = 0; b < FNSUB; ++b) {
        float bm0 = 3.4e38f, bm1 = 3.4e38f;
        #pragma unroll
        for (int fi = 0; fi < FFPS; ++fi) {
            const float4 pp = base[(b * FFPS + fi) * FCH];
            const v2f p0 = { pp.x, pp.y }, p1 = { pp.z, pp.w };
            v2f e0, s0, e1, s1, f0, u0, f1, u1;
            FPK_ADD(e0, qva, p0); FPK_MUL(s0, e0, e0);
            FPK_ADD(e1, qva, p1); FPK_MUL(s1, e1, e1);
            FPK_ADD(f0, qvb, p0); FPK_MUL(u0, f0, f0);
            FPK_ADD(f1, qvb, p1); FPK_MUL(u1, f1, f1);
            const float d0a = __fadd_rn(s0.x, s0.y), d1a = __fadd_rn(s1.x, s1.y);
            const float d0b = __fadd_rn(u0.x, u0.y), d1b = __fadd_rn(u1.x, u1.y);
            FMIN3(bm0, d0a, d1a, bm0); FMIN3(bm1, d0b, d1b, bm1);
        }
        if (bm0 < run0) { run0 = bm0; bb0 = b; }
        if (bm1 < run1) { run1 = bm1; bb1 = b; }
    }
    auto rescan = [&](float best, int bbx, v2f qv) -> int {
        int midx = 0x7fffffff;
        #pragma unroll
        for (int fi = 0; fi < FFPS; ++fi) {
            const float4 pp = base[(bbx * FFPS + fi) * FCH];
            const v2f p0 = { pp.x, pp.y }, p1 = { pp.z, pp.w };
            v2f e0, s0, e1, s1;
            FPK_ADD(e0, qv, p0); FPK_MUL(s0, e0, e0);
            FPK_ADD(e1, qv, p1); FPK_MUL(s1, e1, e1);
            const float d0 = __fadd_rn(s0.x, s0.y), d1 = __fadd_rn(s1.x, s1.y);
            const int gi = c * FLCH + bbx * FSUB + fi * 2;
            if (d0 == best && gi < midx) midx = gi;
            if (d1 == best && gi + 1 < midx) midx = gi + 1;
        }
        return midx;
    };
    int mi0 = rescan(run0, bb0, qva), mi1 = rescan(run1, bb1, qvb);
    float v0 = run0, v1 = run1;
    #pragma unroll
    for (int s = 1; s < FCH; s <<= 1) {
        const float o0 = __shfl_xor(v0, s); const int j0 = __shfl_xor(mi0, s);
        if (o0 < v0 || (o0 == v0 && j0 < mi0)) { v0 = o0; mi0 = j0; }
        const float o1 = __shfl_xor(v1, s); const int j1 = __shfl_xor(mi1, s);
        if (o1 < v1 || (o1 == v1 && j1 < mi1)) { v1 = o1; mi1 = j1; }
    }
    if (c == 0) {
        mi0 = mi0 < N_M ? mi0 : N_M - 1; mi1 = mi1 < N_M ? mi1 : N_M - 1;
        if (qi0 < N_Q) { const float2 bp = mz[mi0];
            out[2*qi0] = bp.x; out[2*qi0+1] = bp.y; out[2*N_Q+qi0] = ts[mi0]; }
        if (qi1 < N_Q) { const float2 bp = mz[mi1];
            out[2*qi1] = bp.x; out[2*qi1+1] = bp.y; out[2*N_Q+qi1] = ts[mi1]; }
    }
}

extern "C" void kernel_launch(void* const* d_in, const int* in_sizes, int n_in,
                              void* d_out, int out_size, void* d_ws, size_t ws_size,
                              hipStream_t stream) {
    const float* q    = (const float*)d_in[0];  // euclidean_data [N,2]
    const float* maze = (const float*)d_in[1];  // maze_points   [M,2]
    const float* ts   = (const float*)d_in[2];  // ts_proj       [M]
    float* out = (float*)d_out;                 // [N*2] proj_pos ++ [N] linear_pos

    if (ws_size >= (size_t)WS_BYTES) {
        setup_soa<<<(NPAD + 255) / 256, 256, 0, stream>>>(maze, (float*)d_ws);
        nn_scan<<<(N_Q + 63) / 64, 256, 0, stream>>>(q, maze, ts,
                                                     (const float*)d_ws, out);
    } else {
        nn1_fallback<<<(N_Q + 63) / 64, 256, 0, stream>>>(q, maze, ts, out);
    }
}